// Round 1
// baseline (329.832 us; speedup 1.0000x reference)
//
#include <hip/hip_runtime.h>

#define N_TOTAL 8192
#define B_HALF  4096
#define D       256
#define BM      64
#define BK      32
#define NT      (N_TOTAL / BM)   // 128 tiles per side

// ws layout:
//   [0..8)      double sumsq
//   [8..16)     double main signed sum
//   [16..1040)  float colsum[256]
//   [2048..2052) float g2  ( log2(e) / (16*bandwidth) )
//   [4096..)    float sq[8192]

// ---------------------------------------------------------------- pass 1
__global__ __launch_bounds__(256)
void pre_kernel(const float* __restrict__ src, const float* __restrict__ tar,
                float* __restrict__ sq, float* __restrict__ colsum,
                double* __restrict__ sumsq) {
    __shared__ float cs[D];
    int t = threadIdx.x;
    cs[t] = 0.f;
    __syncthreads();

    int lane = t & 63, w = t >> 6;
    int rowBase = blockIdx.x * 32 + w * 8;
    float4 csum = make_float4(0.f, 0.f, 0.f, 0.f);
    float sqacc = 0.f;
    for (int it = 0; it < 8; ++it) {
        int r = rowBase + it;
        const float* rowp = (r < B_HALF) ? (src + (size_t)r * D)
                                         : (tar + (size_t)(r - B_HALF) * D);
        float4 v = *(const float4*)(rowp + lane * 4);
        csum.x += v.x; csum.y += v.y; csum.z += v.z; csum.w += v.w;
        float s = v.x * v.x + v.y * v.y + v.z * v.z + v.w * v.w;
        #pragma unroll
        for (int off = 32; off; off >>= 1) s += __shfl_xor(s, off, 64);
        if (lane == 0) { sq[r] = s; sqacc += s; }
    }
    atomicAdd(&cs[lane * 4 + 0], csum.x);
    atomicAdd(&cs[lane * 4 + 1], csum.y);
    atomicAdd(&cs[lane * 4 + 2], csum.z);
    atomicAdd(&cs[lane * 4 + 3], csum.w);
    if (lane == 0) atomicAdd(sumsq, (double)sqacc);
    __syncthreads();
    atomicAdd(&colsum[t], cs[t]);
}

// ---------------------------------------------------------------- bandwidth
__global__ void bw_kernel(const float* __restrict__ colsum,
                          const double* __restrict__ sumsq,
                          float* __restrict__ g2) {
    double s2 = 0.0;
    for (int k = 0; k < D; ++k) { double c = colsum[k]; s2 += c * c; }
    double sumL2 = 2.0 * (double)N_TOTAL * (*sumsq) - 2.0 * s2;
    double nn = (double)N_TOTAL * (double)N_TOTAL - (double)N_TOTAL;
    double bw = sumL2 / nn / 4.0;                 // KERNEL_MUL**(5//2) = 4
    *g2 = (float)(1.4426950408889634 / (16.0 * bw));
}

// ---------------------------------------------------------------- main pass
__global__ __launch_bounds__(256)
void mmd_main(const float* __restrict__ src, const float* __restrict__ tar,
              const float* __restrict__ sq, const float* __restrict__ g2p,
              double* __restrict__ outsum) {
    // linear block id -> upper-triangular tile (ti, tj), tj >= ti
    int id = blockIdx.x;
    int ti = (int)((2.0 * NT + 1.0 -
                    sqrt((2.0 * NT + 1.0) * (2.0 * NT + 1.0) - 8.0 * (double)id)) * 0.5);
    if (ti < 0) ti = 0;
    if (ti > NT - 1) ti = NT - 1;
    while (ti > 0 && id < ti * NT - ti * (ti - 1) / 2) --ti;
    while (id >= (ti + 1) * NT - (ti + 1) * ti / 2) ++ti;
    int tj = ti + (id - (ti * NT - ti * (ti - 1) / 2));

    const float* Abase = (ti < NT / 2) ? (src + (size_t)ti * BM * D)
                                       : (tar + (size_t)(ti - NT / 2) * BM * D);
    const float* Bbase = (tj < NT / 2) ? (src + (size_t)tj * BM * D)
                                       : (tar + (size_t)(tj - NT / 2) * BM * D);

    __shared__ __attribute__((aligned(16))) float As[BK][68];
    __shared__ __attribute__((aligned(16))) float Bs[BK][68];

    int t = threadIdx.x;
    int tx = t & 15, ty = t >> 4;

    float acc[4][4];
    #pragma unroll
    for (int m = 0; m < 4; ++m)
        #pragma unroll
        for (int n = 0; n < 4; ++n) acc[m][n] = 0.f;

    for (int kk = 0; kk < D; kk += BK) {
        // load 64x32 A and B tiles, store k-major (transposed) into LDS
        #pragma unroll
        for (int p = 0; p < 2; ++p) {
            int q = t + p * 256;           // float4 index, 0..511
            int row = q >> 3;              // 0..63
            int kc = (q & 7) * 4;          // 0,4,..,28
            float4 a = *(const float4*)(Abase + (size_t)row * D + kk + kc);
            float4 b = *(const float4*)(Bbase + (size_t)row * D + kk + kc);
            As[kc + 0][row] = a.x; As[kc + 1][row] = a.y;
            As[kc + 2][row] = a.z; As[kc + 3][row] = a.w;
            Bs[kc + 0][row] = b.x; Bs[kc + 1][row] = b.y;
            Bs[kc + 2][row] = b.z; Bs[kc + 3][row] = b.w;
        }
        __syncthreads();
        #pragma unroll
        for (int k = 0; k < BK; ++k) {
            float4 a = *(const float4*)&As[k][ty * 4];
            float4 b = *(const float4*)&Bs[k][tx * 4];
            float av[4] = {a.x, a.y, a.z, a.w};
            float bv[4] = {b.x, b.y, b.z, b.w};
            #pragma unroll
            for (int m = 0; m < 4; ++m)
                #pragma unroll
                for (int n = 0; n < 4; ++n)
                    acc[m][n] = fmaf(av[m], bv[n], acc[m][n]);
        }
        __syncthreads();
    }

    // epilogue: L2 -> 5-kernel RBF sum -> signed accumulate
    float g2 = *g2p;
    float sqi[4], sqj[4];
    #pragma unroll
    for (int m = 0; m < 4; ++m) sqi[m] = sq[ti * BM + ty * 4 + m];
    #pragma unroll
    for (int n = 0; n < 4; ++n) sqj[n] = sq[tj * BM + tx * 4 + n];

    float local = 0.f;
    #pragma unroll
    for (int m = 0; m < 4; ++m) {
        #pragma unroll
        for (int n = 0; n < 4; ++n) {
            float L2 = fmaxf(sqi[m] + sqj[n] - 2.f * acc[m][n], 0.f);
            float u = exp2f(-L2 * g2);     // exp(-L2/(16*bw))
            float u2 = u * u;
            float u4 = u2 * u2;
            float u8 = u4 * u4;
            float u16 = u8 * u8;
            local += u + u2 + u4 + u8 + u16;
        }
    }

    float scale = ((ti < NT / 2) == (tj < NT / 2)) ? 1.f : -1.f;
    if (ti != tj) scale *= 2.f;

    // block reduce
    #pragma unroll
    for (int off = 32; off; off >>= 1) local += __shfl_xor(local, off, 64);
    __shared__ float wsum[4];
    int lane = t & 63, w = t >> 6;
    if (lane == 0) wsum[w] = local;
    __syncthreads();
    if (t == 0) {
        double bsum = (double)wsum[0] + wsum[1] + wsum[2] + wsum[3];
        atomicAdd(outsum, (double)scale * bsum);
    }
}

// ---------------------------------------------------------------- finalize
__global__ void final_kernel(const double* __restrict__ outsum, float* __restrict__ out) {
    out[0] = (float)(outsum[0] / ((double)B_HALF * (double)B_HALF));
}

extern "C" void kernel_launch(void* const* d_in, const int* in_sizes, int n_in,
                              void* d_out, int out_size, void* d_ws, size_t ws_size,
                              hipStream_t stream) {
    const float* src = (const float*)d_in[0];
    const float* tar = (const float*)d_in[1];
    float* out = (float*)d_out;

    char* ws = (char*)d_ws;
    double* sumsq  = (double*)(ws + 0);
    double* mainsum = (double*)(ws + 8);
    float* colsum = (float*)(ws + 16);
    float* g2     = (float*)(ws + 2048);
    float* sq     = (float*)(ws + 4096);

    hipMemsetAsync(ws, 0, 2048, stream);

    pre_kernel<<<256, 256, 0, stream>>>(src, tar, sq, colsum, sumsq);
    bw_kernel<<<1, 1, 0, stream>>>(colsum, sumsq, g2);
    int nblocks = NT * (NT + 1) / 2;   // 8256
    mmd_main<<<nblocks, 256, 0, stream>>>(src, tar, sq, g2, mainsum);
    final_kernel<<<1, 1, 0, stream>>>(mainsum, out);
}

// Round 2
// 168.411 us; speedup vs baseline: 1.9585x; 1.9585x over previous
//
#include <hip/hip_runtime.h>

#define D      256
#define NROWS  8192
#define BHALF  4096
#define TILE   128
#define NT2    (NROWS / TILE)          // 64
#define NBLK   (NT2 * (NT2 + 1) / 2)   // 2080

typedef __attribute__((ext_vector_type(8))) short  short8;
typedef __attribute__((ext_vector_type(4))) float  f32x4;

// ws layout:
//   [0..8)       double sumsq
//   [8..16)      double main signed sum
//   [16..1040)   float colsum[256]
//   [2048..2052) float g2  ( log2(e) / (16*bandwidth) )
//   [4096..36864) float sq[8192]
//   [40960..)    bf16 Tb[8192][256]  (4 MB, if ws_size permits)

__device__ __forceinline__ unsigned short f2bf(float f) {
    unsigned u = __builtin_bit_cast(unsigned, f);
    unsigned r = (u + 0x7fffu + ((u >> 16) & 1u)) >> 16;   // RNE (no NaN in data)
    return (unsigned short)r;
}

// ---------------------------------------------------------------- pass 1
__global__ __launch_bounds__(256)
void pre_kernel(const float* __restrict__ src, const float* __restrict__ tar,
                float* __restrict__ sq, float* __restrict__ colsum,
                double* __restrict__ sumsq, unsigned short* __restrict__ Tb) {
    __shared__ float cs[D];
    int t = threadIdx.x;
    cs[t] = 0.f;
    __syncthreads();

    int lane = t & 63, w = t >> 6;
    int rowBase = blockIdx.x * 32 + w * 8;
    float4 csum = make_float4(0.f, 0.f, 0.f, 0.f);
    float sqacc = 0.f;
    for (int it = 0; it < 8; ++it) {
        int r = rowBase + it;
        const float* rowp = (r < BHALF) ? (src + (size_t)r * D)
                                        : (tar + (size_t)(r - BHALF) * D);
        float4 v = *(const float4*)(rowp + lane * 4);
        if (Tb) {
            ushort4 h;
            h.x = f2bf(v.x); h.y = f2bf(v.y); h.z = f2bf(v.z); h.w = f2bf(v.w);
            *(ushort4*)(Tb + (size_t)r * D + lane * 4) = h;
        }
        csum.x += v.x; csum.y += v.y; csum.z += v.z; csum.w += v.w;
        float s = v.x * v.x + v.y * v.y + v.z * v.z + v.w * v.w;
        #pragma unroll
        for (int off = 32; off; off >>= 1) s += __shfl_xor(s, off, 64);
        if (lane == 0) { sq[r] = s; sqacc += s; }
    }
    atomicAdd(&cs[lane * 4 + 0], csum.x);
    atomicAdd(&cs[lane * 4 + 1], csum.y);
    atomicAdd(&cs[lane * 4 + 2], csum.z);
    atomicAdd(&cs[lane * 4 + 3], csum.w);
    if (lane == 0) atomicAdd(sumsq, (double)sqacc);
    __syncthreads();
    atomicAdd(&colsum[t], cs[t]);
}

// ---------------------------------------------------------------- bandwidth (1 wave)
__global__ void bw_kernel(const float* __restrict__ colsum,
                          const double* __restrict__ sumsq,
                          float* __restrict__ g2) {
    int l = threadIdx.x;                 // 64 threads
    float4 c = *(const float4*)(colsum + l * 4);
    float s = c.x * c.x + c.y * c.y + c.z * c.z + c.w * c.w;
    #pragma unroll
    for (int off = 32; off; off >>= 1) s += __shfl_xor(s, off, 64);
    if (l == 0) {
        double s2 = (double)s;
        double sumL2 = 2.0 * (double)NROWS * (*sumsq) - 2.0 * s2;
        double nn = (double)NROWS * (double)NROWS - (double)NROWS;
        double bw = sumL2 / nn / 4.0;            // KERNEL_MUL**(5//2) = 4
        *g2 = (float)(1.4426950408889634 / (16.0 * bw));
    }
}

// ---------------------------------------------------------------- main MFMA pass
template<bool BF16>
__global__ __launch_bounds__(256)
void mmd_mfma(const float* __restrict__ src, const float* __restrict__ tar,
              const unsigned short* __restrict__ Tb,
              const float* __restrict__ sq, const float* __restrict__ g2p,
              double* __restrict__ outsum)
{
    // linear block id -> upper-triangular tile (ti, tj), tj >= ti
    int id = blockIdx.x;
    int ti = 0, rem = id;
    while (rem >= NT2 - ti) { rem -= NT2 - ti; ++ti; }
    int tj = ti + rem;

    int t = threadIdx.x, lane = t & 63, wid = t >> 6;
    int wi = wid >> 1, wj = wid & 1;
    int rowA = ti * TILE + wi * 64;     // wave's 64-row band (A side)
    int rowB = tj * TILE + wj * 64;     // wave's 64-col band (B side)
    int lr = lane & 15, lk = lane >> 4; // frag row/col-in-16, k-group

    const unsigned short* PaB = nullptr; const unsigned short* PbB = nullptr;
    const float* PaF = nullptr; const float* PbF = nullptr;
    if (BF16) {
        PaB = Tb + (size_t)rowA * D;
        PbB = Tb + (size_t)rowB * D;
    } else {
        PaF = (ti < NT2 / 2) ? src + (size_t)rowA * D : tar + (size_t)(rowA - BHALF) * D;
        PbF = (tj < NT2 / 2) ? src + (size_t)rowB * D : tar + (size_t)(rowB - BHALF) * D;
    }

    f32x4 acc[4][4];
    #pragma unroll
    for (int m = 0; m < 4; ++m)
        #pragma unroll
        for (int n = 0; n < 4; ++n)
            acc[m][n] = (f32x4){0.f, 0.f, 0.f, 0.f};

    #pragma unroll
    for (int kk = 0; kk < D; kk += 32) {
        short8 a[4], b[4];
        #pragma unroll
        for (int m = 0; m < 4; ++m) {
            int offA = (m * 16 + lr) * D + kk + lk * 8;
            int offB = offA;            // same intra-tile pattern for B band
            if (BF16) {
                a[m] = *(const short8*)(PaB + offA);
                b[m] = *(const short8*)(PbB + offB);
            } else {
                float4 f0 = *(const float4*)(PaF + offA);
                float4 f1 = *(const float4*)(PaF + offA + 4);
                float4 g0 = *(const float4*)(PbF + offB);
                float4 g1 = *(const float4*)(PbF + offB + 4);
                short8 va, vb;
                va[0] = (short)f2bf(f0.x); va[1] = (short)f2bf(f0.y);
                va[2] = (short)f2bf(f0.z); va[3] = (short)f2bf(f0.w);
                va[4] = (short)f2bf(f1.x); va[5] = (short)f2bf(f1.y);
                va[6] = (short)f2bf(f1.z); va[7] = (short)f2bf(f1.w);
                vb[0] = (short)f2bf(g0.x); vb[1] = (short)f2bf(g0.y);
                vb[2] = (short)f2bf(g0.z); vb[3] = (short)f2bf(g0.w);
                vb[4] = (short)f2bf(g1.x); vb[5] = (short)f2bf(g1.y);
                vb[6] = (short)f2bf(g1.z); vb[7] = (short)f2bf(g1.w);
                a[m] = va; b[m] = vb;
            }
        }
        #pragma unroll
        for (int m = 0; m < 4; ++m)
            #pragma unroll
            for (int n = 0; n < 4; ++n)
                acc[m][n] = __builtin_amdgcn_mfma_f32_16x16x32_bf16(
                                a[m], b[n], acc[m][n], 0, 0, 0);
    }

    // epilogue: L2 -> 5-kernel RBF sum (u+u^2+u^4+u^8+u^16) -> signed accumulate
    float g2 = *g2p;
    float sqj[4];
    #pragma unroll
    for (int n = 0; n < 4; ++n) sqj[n] = sq[rowB + n * 16 + lr];

    float local = 0.f;
    #pragma unroll
    for (int m = 0; m < 4; ++m) {
        #pragma unroll
        for (int r = 0; r < 4; ++r) {
            float si = sq[rowA + m * 16 + lk * 4 + r];
            #pragma unroll
            for (int n = 0; n < 4; ++n) {
                float L2 = fmaxf(si + sqj[n] - 2.f * acc[m][n][r], 0.f);
                float u = exp2f(-L2 * g2);
                float u2 = u * u, u4 = u2 * u2, u8 = u4 * u4, u16 = u8 * u8;
                local += u + u2 + u4 + u8 + u16;
            }
        }
    }

    #pragma unroll
    for (int off = 32; off; off >>= 1) local += __shfl_xor(local, off, 64);
    __shared__ float wsum[4];
    if (lane == 0) wsum[wid] = local;
    __syncthreads();
    if (t == 0) {
        float scale = ((ti < NT2 / 2) == (tj < NT2 / 2)) ? 1.f : -1.f;
        if (ti != tj) scale *= 2.f;
        double bsum = (double)wsum[0] + wsum[1] + wsum[2] + wsum[3];
        atomicAdd(outsum, (double)scale * bsum);
    }
}

// ---------------------------------------------------------------- finalize
__global__ void final_kernel(const double* __restrict__ outsum, float* __restrict__ out) {
    out[0] = (float)(outsum[0] / ((double)BHALF * (double)BHALF));
}

extern "C" void kernel_launch(void* const* d_in, const int* in_sizes, int n_in,
                              void* d_out, int out_size, void* d_ws, size_t ws_size,
                              hipStream_t stream) {
    const float* src = (const float*)d_in[0];
    const float* tar = (const float*)d_in[1];
    float* out = (float*)d_out;

    char* ws = (char*)d_ws;
    double* sumsq   = (double*)(ws + 0);
    double* mainsum = (double*)(ws + 8);
    float*  colsum  = (float*)(ws + 16);
    float*  g2      = (float*)(ws + 2048);
    float*  sq      = (float*)(ws + 4096);
    unsigned short* Tb = (unsigned short*)(ws + 40960);

    size_t need = 40960 + (size_t)NROWS * D * 2;  // ~4.2 MB
    bool usebf = (ws_size >= need);

    hipMemsetAsync(ws, 0, 2048, stream);

    pre_kernel<<<256, 256, 0, stream>>>(src, tar, sq, colsum, sumsq,
                                        usebf ? Tb : nullptr);
    bw_kernel<<<1, 64, 0, stream>>>(colsum, sumsq, g2);
    if (usebf)
        mmd_mfma<true><<<NBLK, 256, 0, stream>>>(src, tar, Tb, sq, g2, mainsum);
    else
        mmd_mfma<false><<<NBLK, 256, 0, stream>>>(src, tar, nullptr, sq, g2, mainsum);
    final_kernel<<<1, 1, 0, stream>>>(mainsum, out);
}

// Round 3
// 152.955 us; speedup vs baseline: 2.1564x; 1.1010x over previous
//
#include <hip/hip_runtime.h>

#define D      256
#define NROWS  8192
#define BHALF  4096
#define TILE   128
#define BK     64
#define NT2    (NROWS / TILE)          // 64
#define NBLK   (NT2 * (NT2 + 1) / 2)   // 2080

typedef __attribute__((ext_vector_type(8))) short  short8;
typedef __attribute__((ext_vector_type(4))) float  f32x4;

// ws layout (memset zeroes [0..2048)):
//   0    double mainsum      (re-zeroed by bw_kernel)
//   8    double sumsq
//   16   unsigned counter    (re-zeroed by bw_kernel)
//   24   float g2
//   32   float colsum[256]            -> ends 1056
//   4096 float sq[8192]               -> ends 36864
//   36864 bf16 Tb[8192][256] (4 MB)   -> ends 4231168  (< proven 4235264)

__device__ __forceinline__ unsigned short f2bf(float f) {
    unsigned u = __builtin_bit_cast(unsigned, f);
    unsigned r = (u + 0x7fffu + ((u >> 16) & 1u)) >> 16;   // RNE (no NaN in data)
    return (unsigned short)r;
}

__device__ __forceinline__ void gload_lds16(const unsigned short* g, unsigned short* l) {
    __builtin_amdgcn_global_load_lds(
        (const __attribute__((address_space(1))) unsigned int*)g,
        (__attribute__((address_space(3))) unsigned int*)l,
        16, 0, 0);
}

// ---------------------------------------------------------------- pass 1
__global__ __launch_bounds__(256)
void pre_kernel(const float* __restrict__ src, const float* __restrict__ tar,
                float* __restrict__ sq, float* __restrict__ colsum,
                double* __restrict__ sumsq, unsigned short* __restrict__ Tb) {
    __shared__ float cs[D];
    int t = threadIdx.x;
    cs[t] = 0.f;
    __syncthreads();

    int lane = t & 63, w = t >> 6;
    int rowBase = blockIdx.x * 32 + w * 8;

    // batch the 8 independent row loads first (hide latency)
    float4 v[8];
    #pragma unroll
    for (int it = 0; it < 8; ++it) {
        int r = rowBase + it;
        const float* rowp = (r < BHALF) ? (src + (size_t)r * D)
                                        : (tar + (size_t)(r - BHALF) * D);
        v[it] = *(const float4*)(rowp + lane * 4);
    }

    float4 csum = make_float4(0.f, 0.f, 0.f, 0.f);
    float sqacc = 0.f;
    #pragma unroll
    for (int it = 0; it < 8; ++it) {
        int r = rowBase + it;
        ushort4 h;
        h.x = f2bf(v[it].x); h.y = f2bf(v[it].y);
        h.z = f2bf(v[it].z); h.w = f2bf(v[it].w);
        *(ushort4*)(Tb + (size_t)r * D + lane * 4) = h;
        csum.x += v[it].x; csum.y += v[it].y; csum.z += v[it].z; csum.w += v[it].w;
        float s = v[it].x * v[it].x + v[it].y * v[it].y +
                  v[it].z * v[it].z + v[it].w * v[it].w;
        #pragma unroll
        for (int off = 32; off; off >>= 1) s += __shfl_xor(s, off, 64);
        if (lane == 0) { sq[r] = s; sqacc += s; }
    }
    atomicAdd(&cs[lane * 4 + 0], csum.x);
    atomicAdd(&cs[lane * 4 + 1], csum.y);
    atomicAdd(&cs[lane * 4 + 2], csum.z);
    atomicAdd(&cs[lane * 4 + 3], csum.w);
    if (lane == 0) atomicAdd(sumsq, (double)sqacc);
    __syncthreads();
    atomicAdd(&colsum[t], cs[t]);
}

// ---------------------------------------------------------------- bandwidth
__global__ void bw_kernel(const float* __restrict__ colsum,
                          const double* __restrict__ sumsq,
                          float* __restrict__ g2,
                          double* __restrict__ mainsum,
                          unsigned* __restrict__ counter) {
    int l = threadIdx.x;                 // 64 threads
    float4 c = *(const float4*)(colsum + l * 4);
    float s = c.x * c.x + c.y * c.y + c.z * c.z + c.w * c.w;
    #pragma unroll
    for (int off = 32; off; off >>= 1) s += __shfl_xor(s, off, 64);
    if (l == 0) {
        double s2 = (double)s;
        double sumL2 = 2.0 * (double)NROWS * (*sumsq) - 2.0 * s2;
        double nn = (double)NROWS * (double)NROWS - (double)NROWS;
        double bw = sumL2 / nn / 4.0;            // KERNEL_MUL**(5//2) = 4
        *g2 = (float)(1.4426950408889634 / (16.0 * bw));
        *mainsum = 0.0;
        *counter = 0u;
    }
}

// ---------------------------------------------------------------- main
__global__ __launch_bounds__(256)
void mmd_main(const unsigned short* __restrict__ Tb,
              const float* __restrict__ sq, const float* __restrict__ g2p,
              double* __restrict__ mainsum, unsigned* __restrict__ counter,
              float* __restrict__ out) {
    __shared__ unsigned short As[2][TILE * BK];   // 16 KB per buf
    __shared__ unsigned short Bs[2][TILE * BK];

    // XCD-aware bijective swizzle (2080 % 8 == 0), then upper-tri mapping
    int bid = blockIdx.x;
    int wg = (bid & 7) * (NBLK / 8) + (bid >> 3);
    int ti = 0, rem = wg;
    while (rem >= NT2 - ti) { rem -= NT2 - ti; ++ti; }
    int tj = ti + rem;

    int t = threadIdx.x, lane = t & 63, wid = t >> 6;
    int wi = wid >> 1, wj = wid & 1;
    int lr = lane & 15, lk = lane >> 4;

    const unsigned short* gA = Tb + (size_t)(ti * TILE) * D;
    const unsigned short* gB = Tb + (size_t)(tj * TILE) * D;

    // prefetch sq values for the epilogue (independent of staging)
    int rowA = ti * TILE + wi * 64;
    int rowB = tj * TILE + wj * 64;
    float sqj[4], sqi[4][4];
    #pragma unroll
    for (int n = 0; n < 4; ++n) sqj[n] = sq[rowB + n * 16 + lr];
    #pragma unroll
    for (int m = 0; m < 4; ++m)
        #pragma unroll
        for (int r = 0; r < 4; ++r)
            sqi[m][r] = sq[rowA + m * 16 + lk * 4 + r];

    // staging: LDS is linear [row][slot], global source col pre-swizzled
    // (slot s of row holds global chunk s ^ (row&7)) — rule #21 involution
    auto stage = [&](int buf, int ks) {
        #pragma unroll
        for (int p = 0; p < 4; ++p) {
            int q = p * 256 + t;           // 1024 chunks of 16 B per tile
            int row = q >> 3, c = q & 7;
            int scol = ks * BK + ((c ^ (row & 7)) << 3);
            gload_lds16(gA + (size_t)row * D + scol, &As[buf][q << 3]);
            gload_lds16(gB + (size_t)row * D + scol, &Bs[buf][q << 3]);
        }
    };

    f32x4 acc[4][4];
    #pragma unroll
    for (int m = 0; m < 4; ++m)
        #pragma unroll
        for (int n = 0; n < 4; ++n)
            acc[m][n] = (f32x4){0.f, 0.f, 0.f, 0.f};

    stage(0, 0);
    asm volatile("s_waitcnt vmcnt(0)" ::: "memory");
    __syncthreads();

    int cur = 0;
    for (int ks = 0; ks < 4; ++ks) {
        if (ks < 3) stage(cur ^ 1, ks + 1);
        #pragma unroll
        for (int h = 0; h < 2; ++h) {             // two K=32 halves of BK=64
            short8 a[4], b[4];
            #pragma unroll
            for (int m = 0; m < 4; ++m) {
                int rA = wi * 64 + m * 16 + lr;
                int rB = wj * 64 + m * 16 + lr;
                int ca = h * 4 + lk;              // logical 16B-chunk index
                a[m] = *(const short8*)&As[cur][rA * 64 + ((ca ^ (rA & 7)) << 3)];
                b[m] = *(const short8*)&Bs[cur][rB * 64 + ((ca ^ (rB & 7)) << 3)];
            }
            #pragma unroll
            for (int m = 0; m < 4; ++m)
                #pragma unroll
                for (int n = 0; n < 4; ++n)
                    acc[m][n] = __builtin_amdgcn_mfma_f32_16x16x32_bf16(
                                    a[m], b[n], acc[m][n], 0, 0, 0);
        }
        __syncthreads();   // drains vmcnt (next buf staged) + all reads of cur done
        cur ^= 1;
    }

    // epilogue: L2 -> u + u^2 + u^4 + u^8 + u^16 -> signed accumulate
    float g2 = *g2p;
    float local = 0.f;
    #pragma unroll
    for (int m = 0; m < 4; ++m) {
        #pragma unroll
        for (int r = 0; r < 4; ++r) {
            float si = sqi[m][r];
            #pragma unroll
            for (int n = 0; n < 4; ++n) {
                float L2 = fmaxf(si + sqj[n] - 2.f * acc[m][n][r], 0.f);
                float u = exp2f(-L2 * g2);
                float u2 = u * u, u4 = u2 * u2, u8 = u4 * u4, u16 = u8 * u8;
                local += u + u2 + u4 + u8 + u16;
            }
        }
    }

    #pragma unroll
    for (int off = 32; off; off >>= 1) local += __shfl_xor(local, off, 64);
    __shared__ float wsum[4];
    if (lane == 0) wsum[wid] = local;
    __syncthreads();
    if (t == 0) {
        float scale = ((ti < NT2 / 2) == (tj < NT2 / 2)) ? 1.f : -1.f;
        if (ti != tj) scale *= 2.f;
        double bsum = (double)wsum[0] + wsum[1] + wsum[2] + wsum[3];
        atomicAdd(mainsum, (double)scale * bsum);
        __threadfence();
        unsigned old = atomicAdd(counter, 1u);
        if (old == NBLK - 1) {   // last block finalizes (fused final_kernel)
            double tot = atomicAdd(mainsum, 0.0);
            out[0] = (float)(tot / ((double)BHALF * (double)BHALF));
        }
    }
}

extern "C" void kernel_launch(void* const* d_in, const int* in_sizes, int n_in,
                              void* d_out, int out_size, void* d_ws, size_t ws_size,
                              hipStream_t stream) {
    const float* src = (const float*)d_in[0];
    const float* tar = (const float*)d_in[1];
    float* out = (float*)d_out;

    char* ws = (char*)d_ws;
    double*   mainsum = (double*)(ws + 0);
    double*   sumsq   = (double*)(ws + 8);
    unsigned* counter = (unsigned*)(ws + 16);
    float*    g2      = (float*)(ws + 24);
    float*    colsum  = (float*)(ws + 32);
    float*    sq      = (float*)(ws + 4096);
    unsigned short* Tb = (unsigned short*)(ws + 36864);

    hipMemsetAsync(ws, 0, 2048, stream);
    pre_kernel<<<256, 256, 0, stream>>>(src, tar, sq, colsum, sumsq, Tb);
    bw_kernel<<<1, 64, 0, stream>>>(colsum, sumsq, g2, mainsum, counter);
    mmd_main<<<NBLK, 256, 0, stream>>>(Tb, sq, g2, mainsum, counter, out);
}

// Round 4
// 133.599 us; speedup vs baseline: 2.4688x; 1.1449x over previous
//
#include <hip/hip_runtime.h>

#define D      256
#define NROWS  8192
#define BHALF  4096
#define TILE   128
#define NT2    (NROWS / TILE)          // 64
#define NBLK   (NT2 * (NT2 + 1) / 2)   // 2080
#define NGRID  256
#define NBINS  64

typedef __attribute__((ext_vector_type(8))) short  short8;
typedef __attribute__((ext_vector_type(4))) float  f32x4;

// ws layout (memset zeroes [0..2048)):
//   0     double sumsq
//   8     unsigned counter
//   16    double bins[64]          -> ends 528
//   1024  float colsum[256]        -> ends 2048
//   4096  float sq[8192]           -> ends 36864
//   36864 bf16 Tb[8192][256] (4 MB) -> ends 4231168 (proven < ws_size)

__device__ __forceinline__ unsigned short f2bf(float f) {
    unsigned u = __builtin_bit_cast(unsigned, f);
    unsigned r = (u + 0x7fffu + ((u >> 16) & 1u)) >> 16;   // RNE (no NaN in data)
    return (unsigned short)r;
}

__device__ __forceinline__ void gload_lds16(const unsigned short* g, unsigned short* l) {
    __builtin_amdgcn_global_load_lds(
        (const __attribute__((address_space(1))) unsigned int*)g,
        (__attribute__((address_space(3))) unsigned int*)l,
        16, 0, 0);
}

// ---------------------------------------------------------------- pass 1
__global__ __launch_bounds__(256)
void pre_kernel(const float* __restrict__ src, const float* __restrict__ tar,
                float* __restrict__ sq, float* __restrict__ colsum,
                double* __restrict__ sumsq, unsigned short* __restrict__ Tb) {
    __shared__ float cs[D];
    int t = threadIdx.x;
    cs[t] = 0.f;
    __syncthreads();

    int lane = t & 63, w = t >> 6;
    int rowBase = blockIdx.x * 32 + w * 8;

    float4 v[8];
    #pragma unroll
    for (int it = 0; it < 8; ++it) {
        int r = rowBase + it;
        const float* rowp = (r < BHALF) ? (src + (size_t)r * D)
                                        : (tar + (size_t)(r - BHALF) * D);
        v[it] = *(const float4*)(rowp + lane * 4);
    }

    float4 csum = make_float4(0.f, 0.f, 0.f, 0.f);
    float sqacc = 0.f;
    #pragma unroll
    for (int it = 0; it < 8; ++it) {
        int r = rowBase + it;
        ushort4 h;
        h.x = f2bf(v[it].x); h.y = f2bf(v[it].y);
        h.z = f2bf(v[it].z); h.w = f2bf(v[it].w);
        *(ushort4*)(Tb + (size_t)r * D + lane * 4) = h;
        csum.x += v[it].x; csum.y += v[it].y; csum.z += v[it].z; csum.w += v[it].w;
        float s = v[it].x * v[it].x + v[it].y * v[it].y +
                  v[it].z * v[it].z + v[it].w * v[it].w;
        #pragma unroll
        for (int off = 32; off; off >>= 1) s += __shfl_xor(s, off, 64);
        if (lane == 0) { sq[r] = s; sqacc += s; }
    }
    atomicAdd(&cs[lane * 4 + 0], csum.x);
    atomicAdd(&cs[lane * 4 + 1], csum.y);
    atomicAdd(&cs[lane * 4 + 2], csum.z);
    atomicAdd(&cs[lane * 4 + 3], csum.w);
    if (lane == 0) atomicAdd(sumsq, (double)sqacc);
    __syncthreads();
    atomicAdd(&colsum[t], cs[t]);
}

// ---------------------------------------------------------------- main (persistent)
__global__ __launch_bounds__(256)
void mmd_main(const unsigned short* __restrict__ Tb,
              const float* __restrict__ sq, const float* __restrict__ colsum,
              const double* __restrict__ sumsq,
              double* __restrict__ bins, unsigned* __restrict__ counter,
              float* __restrict__ out)
{
    __shared__ unsigned short As[TILE * D];   // 64 KB  (full-K A panel)
    __shared__ unsigned short Bs[TILE * D];   // 64 KB  (full-K B panel)

    int t = threadIdx.x, lane = t & 63, wid = t >> 6;
    int wi = wid >> 1, wj = wid & 1;
    int lr = lane & 15, lk = lane >> 4;

    // XCD-contiguous pair ranges: blocks on the same XCD get adjacent runs
    int bid = blockIdx.x;
    int sw = (bid & 7) * (NGRID / 8) + (bid >> 3);
    int pstart = (int)(((long)sw * NBLK) / NGRID);
    int pend   = (int)(((long)(sw + 1) * NBLK) / NGRID);

    // first pair of the run
    int ti, tj;
    {
        int rem = pstart, a = 0;
        while (rem >= NT2 - a) { rem -= NT2 - a; ++a; }
        ti = a; tj = a + rem;
    }

    // staging: LDS linear [row][chunk], global chunk pre-swizzled c^(row&7)
    auto stageA = [&](int tt) {
        const unsigned short* g = Tb + (size_t)tt * TILE * D;
        #pragma unroll
        for (int p = 0; p < 16; ++p) {
            int q = p * 256 + t;           // 16B-chunk id, 0..4095
            int row = q >> 5, c = q & 31;
            gload_lds16(g + row * D + (((c ^ (row & 7)) << 3)), &As[q << 3]);
        }
    };
    auto stageB = [&](int tt) {
        const unsigned short* g = Tb + (size_t)tt * TILE * D;
        #pragma unroll
        for (int p = 0; p < 16; ++p) {
            int q = p * 256 + t;
            int row = q >> 5, c = q & 31;
            gload_lds16(g + row * D + (((c ^ (row & 7)) << 3)), &Bs[q << 3]);
        }
    };

    stageA(ti);
    stageB(tj);

    // bandwidth -> g2, computed redundantly per block (overlaps first stage)
    float4 c4 = *(const float4*)(colsum + lane * 4);
    float s = c4.x * c4.x + c4.y * c4.y + c4.z * c4.z + c4.w * c4.w;
    #pragma unroll
    for (int off = 32; off; off >>= 1) s += __shfl_xor(s, off, 64);
    double sumL2 = 2.0 * (double)NROWS * (*sumsq) - 2.0 * (double)s;
    double bwd = sumL2 / ((double)NROWS * (double)NROWS - (double)NROWS) / 4.0;
    float g2 = (float)(1.4426950408889634 / (16.0 * bwd));

    for (int p = pstart; p < pend; ++p) {
        asm volatile("s_waitcnt vmcnt(0)" ::: "memory");
        __syncthreads();                       // panels ready

        // epilogue operands: issue early, consumed after MFMA sweep
        int rowA = ti * TILE + wi * 64, rowB = tj * TILE + wj * 64;
        float sqj[4], sqi[4][4];
        #pragma unroll
        for (int n = 0; n < 4; ++n) sqj[n] = sq[rowB + n * 16 + lr];
        #pragma unroll
        for (int m = 0; m < 4; ++m)
            #pragma unroll
            for (int r = 0; r < 4; ++r)
                sqi[m][r] = sq[rowA + m * 16 + lk * 4 + r];

        f32x4 acc[4][4];
        #pragma unroll
        for (int m = 0; m < 4; ++m)
            #pragma unroll
            for (int n = 0; n < 4; ++n)
                acc[m][n] = (f32x4){0.f, 0.f, 0.f, 0.f};

        // full-K MFMA sweep, no barriers inside
        #pragma unroll
        for (int ks = 0; ks < 8; ++ks) {
            short8 a[4], b[4];
            #pragma unroll
            for (int m = 0; m < 4; ++m) {
                int rA = wi * 64 + m * 16 + lr;
                int rB = wj * 64 + m * 16 + lr;
                int ca = ks * 4 + lk;
                a[m] = *(const short8*)&As[rA * D + ((ca ^ (rA & 7)) << 3)];
                b[m] = *(const short8*)&Bs[rB * D + ((ca ^ (rB & 7)) << 3)];
            }
            #pragma unroll
            for (int m = 0; m < 4; ++m)
                #pragma unroll
                for (int n = 0; n < 4; ++n)
                    acc[m][n] = __builtin_amdgcn_mfma_f32_16x16x32_bf16(
                                    a[m], b[n], acc[m][n], 0, 0, 0);
        }
        __syncthreads();                       // all LDS reads done

        // issue next pair's staging now; latency hides under the epilogue
        int nti = ti, ntj = tj;
        if (p + 1 < pend) {
            ntj = tj + 1;
            if (ntj >= NT2) { nti = ti + 1; ntj = nti; }
            stageB(ntj);
            if (nti != ti) stageA(nti);
        }

        // epilogue: L2 -> u + u^2 + u^4 + u^8 + u^16 -> signed bin add
        float local = 0.f;
        #pragma unroll
        for (int m = 0; m < 4; ++m) {
            #pragma unroll
            for (int r = 0; r < 4; ++r) {
                float si = sqi[m][r];
                #pragma unroll
                for (int n = 0; n < 4; ++n) {
                    float L2 = fmaxf(si + sqj[n] - 2.f * acc[m][n][r], 0.f);
                    float u = exp2f(-L2 * g2);
                    float u2 = u * u, u4 = u2 * u2, u8 = u4 * u4, u16 = u8 * u8;
                    local += u + u2 + u4 + u8 + u16;
                }
            }
        }
        #pragma unroll
        for (int off = 32; off; off >>= 1) local += __shfl_xor(local, off, 64);
        if (lane == 0) {
            float scale = ((ti < NT2 / 2) == (tj < NT2 / 2)) ? 1.f : -1.f;
            if (ti != tj) scale *= 2.f;
            atomicAdd(&bins[((bid << 2) + wid) & (NBINS - 1)],
                      (double)(scale * local));
        }
        ti = nti; tj = ntj;
    }

    __syncthreads();
    if (t == 0) {
        __threadfence();
        unsigned old = atomicAdd(counter, 1u);
        if (old == NGRID - 1) {                // last block finalizes
            __threadfence();
            double tot = 0.0;
            for (int i = 0; i < NBINS; ++i)
                tot += ((volatile double*)bins)[i];
            out[0] = (float)(tot / ((double)BHALF * (double)BHALF));
        }
    }
}

extern "C" void kernel_launch(void* const* d_in, const int* in_sizes, int n_in,
                              void* d_out, int out_size, void* d_ws, size_t ws_size,
                              hipStream_t stream) {
    const float* src = (const float*)d_in[0];
    const float* tar = (const float*)d_in[1];
    float* out = (float*)d_out;

    char* ws = (char*)d_ws;
    double*   sumsq   = (double*)(ws + 0);
    unsigned* counter = (unsigned*)(ws + 8);
    double*   bins    = (double*)(ws + 16);
    float*    colsum  = (float*)(ws + 1024);
    float*    sq      = (float*)(ws + 4096);
    unsigned short* Tb = (unsigned short*)(ws + 36864);

    hipMemsetAsync(ws, 0, 2048, stream);
    pre_kernel<<<256, 256, 0, stream>>>(src, tar, sq, colsum, sumsq, Tb);
    mmd_main<<<NGRID, 256, 0, stream>>>(Tb, sq, colsum, sumsq, bins, counter, out);
}